// Round 1
// baseline (727.547 us; speedup 1.0000x reference)
//
#include <hip/hip_runtime.h>

#define WAVE 64

// ---------------- degree count ----------------
__global__ void k_deg(const int* __restrict__ eu, const int* __restrict__ ei,
                      int nE, int nU, int* __restrict__ cnt) {
    int e = blockIdx.x * blockDim.x + threadIdx.x;
    if (e < nE) {
        atomicAdd(&cnt[eu[e]], 1);
        atomicAdd(&cnt[nU + ei[e]], 1);
    }
}

// ---------------- inv sqrt of degree ----------------
__global__ void k_inv(const int* __restrict__ cnt, float* __restrict__ inv, int N) {
    int n = blockIdx.x * blockDim.x + threadIdx.x;
    if (n < N) {
        int c = cnt[n];
        inv[n] = (c > 0) ? (1.0f / sqrtf((float)c)) : 0.0f;
    }
}

// ---------------- scan phase A: per-block sums (block=256) ----------------
__global__ void k_blocksum(const int* __restrict__ cnt, int N, int* __restrict__ bsum) {
    int i = blockIdx.x * 256 + threadIdx.x;
    int v = (i < N) ? cnt[i] : 0;
    #pragma unroll
    for (int o = 32; o > 0; o >>= 1) v += __shfl_down(v, o, WAVE);
    __shared__ int ws[4];
    if ((threadIdx.x & 63) == 0) ws[threadIdx.x >> 6] = v;
    __syncthreads();
    if (threadIdx.x == 0) bsum[blockIdx.x] = ws[0] + ws[1] + ws[2] + ws[3];
}

// ---------------- scan phase B: single-block exclusive scan of block sums ----------------
__global__ void k_scanbsum(int* __restrict__ bsum, int nB) {
    __shared__ int s[1024];
    int t = threadIdx.x;
    int v = (t < nB) ? bsum[t] : 0;
    s[t] = v;
    __syncthreads();
    for (int o = 1; o < 1024; o <<= 1) {
        int x = (t >= o) ? s[t - o] : 0;
        __syncthreads();
        s[t] += x;
        __syncthreads();
    }
    if (t < nB) bsum[t] = s[t] - v;  // exclusive
}

// ---------------- scan phase C: final exclusive positions -> row_ptr & cursor ----------------
__global__ void k_scanfinal(const int* __restrict__ cnt, const int* __restrict__ bsum,
                            int N, int* __restrict__ row_ptr, int* __restrict__ cursor) {
    int i = blockIdx.x * 256 + threadIdx.x;
    int v = (i < N) ? cnt[i] : 0;
    int lane = threadIdx.x & 63, wid = threadIdx.x >> 6;
    int inc = v;
    #pragma unroll
    for (int o = 1; o < WAVE; o <<= 1) {
        int x = __shfl_up(inc, o, WAVE);
        if (lane >= o) inc += x;
    }
    __shared__ int wsum[4];
    if (lane == 63) wsum[wid] = inc;
    __syncthreads();
    int woff = 0;
    for (int w2 = 0; w2 < wid; w2++) woff += wsum[w2];
    int excl = inc - v + woff + bsum[blockIdx.x];
    if (i < N) { row_ptr[i] = excl; cursor[i] = excl; }
    if (i == N - 1) row_ptr[N] = excl + v;
}

// ---------------- CSR scatter ----------------
__global__ void k_scatter(const int* __restrict__ eu, const int* __restrict__ ei,
                          int nE, int nU, const float* __restrict__ inv,
                          int* __restrict__ cursor, int* __restrict__ col,
                          float* __restrict__ w) {
    int e = blockIdx.x * blockDim.x + threadIdx.x;
    if (e >= nE) return;
    int u = eu[e];
    int v = nU + ei[e];
    float wt = inv[u] * inv[v];
    int p1 = atomicAdd(&cursor[v], 1); col[p1] = u; w[p1] = wt;
    int p2 = atomicAdd(&cursor[u], 1); col[p2] = v; w[p2] = wt;
}

// ---------------- x0 = concat(user_emb, item_emb), vectorized ----------------
__global__ void k_initx(const float4* __restrict__ ue, const float4* __restrict__ ie,
                        int nU4, int nTot4, float4* __restrict__ x) {
    int i = blockIdx.x * blockDim.x + threadIdx.x;
    if (i < nTot4) x[i] = (i < nU4) ? ue[i] : ie[i - nU4];
}

// ---------------- batch gather-accumulate: one wave per batch row ----------------
__global__ void k_bacc(const int* __restrict__ users, const int* __restrict__ items,
                       int B, int nU, const float* __restrict__ x,
                       float* __restrict__ acc, int init) {
    int b = blockIdx.x * (blockDim.x >> 6) + (threadIdx.x >> 6);
    int lane = threadIdx.x & 63;
    if (b >= 2 * B) return;
    int row = (b < B) ? users[b] : (nU + items[b - B]);
    float v = x[(size_t)row * 64 + lane];
    size_t o = (size_t)b * 64 + lane;
    if (init) acc[o] = v; else acc[o] += v;
}

// ---------------- SPMM: one wave per dst row, lane = feature ----------------
__global__ void k_spmm(const int* __restrict__ row_ptr, const int* __restrict__ col,
                       const float* __restrict__ w, const float* __restrict__ x,
                       float* __restrict__ y, int N) {
    int row = blockIdx.x * (blockDim.x >> 6) + (threadIdx.x >> 6);
    int lane = threadIdx.x & 63;
    if (row >= N) return;
    int s = row_ptr[row], e = row_ptr[row + 1];
    float acc = 0.0f;
    for (int j = s; j < e; j++) {
        int c = col[j];
        float wt = w[j];
        acc += wt * x[(size_t)c * 64 + lane];
    }
    y[(size_t)row * 64 + lane] = acc;
}

// ---------------- final: gamma[b] = dot(acc_u[b], acc_i[b]) / 25 ----------------
__global__ void k_dot(const float* __restrict__ acc, int B, float* __restrict__ out) {
    int b = blockIdx.x * (blockDim.x >> 6) + (threadIdx.x >> 6);
    int lane = threadIdx.x & 63;
    if (b >= B) return;
    float p = acc[(size_t)b * 64 + lane] * acc[(size_t)(b + B) * 64 + lane];
    #pragma unroll
    for (int o = 32; o > 0; o >>= 1) p += __shfl_down(p, o, WAVE);
    if (lane == 0) out[b] = p * (1.0f / 25.0f);
}

extern "C" void kernel_launch(void* const* d_in, const int* in_sizes, int n_in,
                              void* d_out, int out_size, void* d_ws, size_t ws_size,
                              hipStream_t stream) {
    const int*   users = (const int*)d_in[0];
    const int*   items = (const int*)d_in[1];
    const int*   eu    = (const int*)d_in[2];
    const int*   ei    = (const int*)d_in[3];
    const float* ue    = (const float*)d_in[4];
    const float* ie    = (const float*)d_in[5];
    float* out = (float*)d_out;

    const int D  = 64;
    const int B  = in_sizes[0];
    const int nE = in_sizes[2];
    const int nU = in_sizes[4] / D;
    const int nI = in_sizes[5] / D;
    const int N  = nU + nI;

    // ---- carve workspace (256B-aligned chunks) ----
    char* p = (char*)d_ws;
    auto alloc = [&](size_t bytes) -> void* {
        void* r = (void*)p;
        p += (bytes + 255) & ~(size_t)255;
        return r;
    };
    int*   cnt     = (int*)  alloc((size_t)N * 4);
    int*   row_ptr = (int*)  alloc((size_t)(N + 1) * 4);
    int*   cursor  = (int*)  alloc((size_t)N * 4);
    float* inv     = (float*)alloc((size_t)N * 4);
    int*   col     = (int*)  alloc((size_t)2 * nE * 4);
    float* w       = (float*)alloc((size_t)2 * nE * 4);
    float* xa      = (float*)alloc((size_t)N * D * 4);
    float* xb      = (float*)alloc((size_t)N * D * 4);
    float* acc     = (float*)alloc((size_t)2 * B * D * 4);
    int*   bsum    = (int*)  alloc(4096);  // up to 1024 block sums

    const int nB = (N + 255) / 256;  // 586 for N=150000; must be <= 1024

    // ---- build normalized CSR ----
    hipMemsetAsync(cnt, 0, (size_t)N * 4, stream);
    k_deg<<<(nE + 255) / 256, 256, 0, stream>>>(eu, ei, nE, nU, cnt);
    k_inv<<<(N + 255) / 256, 256, 0, stream>>>(cnt, inv, N);
    k_blocksum<<<nB, 256, 0, stream>>>(cnt, N, bsum);
    k_scanbsum<<<1, 1024, 0, stream>>>(bsum, nB);
    k_scanfinal<<<nB, 256, 0, stream>>>(cnt, bsum, N, row_ptr, cursor);
    k_scatter<<<(nE + 255) / 256, 256, 0, stream>>>(eu, ei, nE, nU, inv, cursor, col, w);

    // ---- x0 and batch accumulator init ----
    int nTot4 = N * (D / 4);
    k_initx<<<(nTot4 + 255) / 256, 256, 0, stream>>>(
        (const float4*)ue, (const float4*)ie, nU * (D / 4), nTot4, (float4*)xa);
    k_bacc<<<(2 * B + 3) / 4, 256, 0, stream>>>(users, items, B, nU, xa, acc, 1);

    // ---- 4 propagation layers ----
    float* xin = xa;
    float* xout = xb;
    for (int l = 0; l < 4; l++) {
        k_spmm<<<(N + 3) / 4, 256, 0, stream>>>(row_ptr, col, w, xin, xout, N);
        k_bacc<<<(2 * B + 3) / 4, 256, 0, stream>>>(users, items, B, nU, xout, acc, 0);
        float* t = xin; xin = xout; xout = t;
    }

    // ---- final dot ----
    k_dot<<<(B + 3) / 4, 256, 0, stream>>>(acc, B, out);
}

// Round 2
// 476.791 us; speedup vs baseline: 1.5259x; 1.5259x over previous
//
#include <hip/hip_runtime.h>

#define WAVE 64

// ---------------- degree count ----------------
__global__ void k_deg(const int* __restrict__ eu, const int* __restrict__ ei,
                      int nE, int nU, int* __restrict__ cnt) {
    int e = blockIdx.x * blockDim.x + threadIdx.x;
    if (e < nE) {
        atomicAdd(&cnt[eu[e]], 1);
        atomicAdd(&cnt[nU + ei[e]], 1);
    }
}

// ---------------- inv sqrt of degree ----------------
__global__ void k_inv(const int* __restrict__ cnt, float* __restrict__ inv, int N) {
    int n = blockIdx.x * blockDim.x + threadIdx.x;
    if (n < N) {
        int c = cnt[n];
        inv[n] = (c > 0) ? (1.0f / sqrtf((float)c)) : 0.0f;
    }
}

// ---------------- scan phase A: per-block sums (block=256) ----------------
__global__ void k_blocksum(const int* __restrict__ cnt, int N, int* __restrict__ bsum) {
    int i = blockIdx.x * 256 + threadIdx.x;
    int v = (i < N) ? cnt[i] : 0;
    #pragma unroll
    for (int o = 32; o > 0; o >>= 1) v += __shfl_down(v, o, WAVE);
    __shared__ int ws[4];
    if ((threadIdx.x & 63) == 0) ws[threadIdx.x >> 6] = v;
    __syncthreads();
    if (threadIdx.x == 0) bsum[blockIdx.x] = ws[0] + ws[1] + ws[2] + ws[3];
}

// ---------------- scan phase B: single-block exclusive scan of block sums ----------------
__global__ void k_scanbsum(int* __restrict__ bsum, int nB) {
    __shared__ int s[1024];
    int t = threadIdx.x;
    int v = (t < nB) ? bsum[t] : 0;
    s[t] = v;
    __syncthreads();
    for (int o = 1; o < 1024; o <<= 1) {
        int x = (t >= o) ? s[t - o] : 0;
        __syncthreads();
        s[t] += x;
        __syncthreads();
    }
    if (t < nB) bsum[t] = s[t] - v;  // exclusive
}

// ---------------- scan phase C: final exclusive positions -> row_ptr & cursor ----------------
__global__ void k_scanfinal(const int* __restrict__ cnt, const int* __restrict__ bsum,
                            int N, int* __restrict__ row_ptr, int* __restrict__ cursor) {
    int i = blockIdx.x * 256 + threadIdx.x;
    int v = (i < N) ? cnt[i] : 0;
    int lane = threadIdx.x & 63, wid = threadIdx.x >> 6;
    int inc = v;
    #pragma unroll
    for (int o = 1; o < WAVE; o <<= 1) {
        int x = __shfl_up(inc, o, WAVE);
        if (lane >= o) inc += x;
    }
    __shared__ int wsum[4];
    if (lane == 63) wsum[wid] = inc;
    __syncthreads();
    int woff = 0;
    for (int w2 = 0; w2 < wid; w2++) woff += wsum[w2];
    int excl = inc - v + woff + bsum[blockIdx.x];
    if (i < N) { row_ptr[i] = excl; cursor[i] = excl; }
    if (i == N - 1) row_ptr[N] = excl + v;
}

// ---------------- CSR scatter: packed (col, w) int2 edges ----------------
__global__ void k_scatter(const int* __restrict__ eu, const int* __restrict__ ei,
                          int nE, int nU, const float* __restrict__ inv,
                          int* __restrict__ cursor, int2* __restrict__ ew) {
    int e = blockIdx.x * blockDim.x + threadIdx.x;
    if (e >= nE) return;
    int u = eu[e];
    int v = nU + ei[e];
    float wt = inv[u] * inv[v];
    int wb = __float_as_int(wt);
    int p1 = atomicAdd(&cursor[v], 1); ew[p1] = make_int2(u, wb);
    int p2 = atomicAdd(&cursor[u], 1); ew[p2] = make_int2(v, wb);
}

// ---------------- x0 = concat(user_emb, item_emb), vectorized ----------------
__global__ void k_initx(const float4* __restrict__ ue, const float4* __restrict__ ie,
                        int nU4, int nTot4, float4* __restrict__ x) {
    int i = blockIdx.x * blockDim.x + threadIdx.x;
    if (i < nTot4) x[i] = (i < nU4) ? ue[i] : ie[i - nU4];
}

// ---------------- batch gather-accumulate: one wave per batch row ----------------
__global__ void k_bacc(const int* __restrict__ users, const int* __restrict__ items,
                       int B, int nU, const float* __restrict__ x,
                       float* __restrict__ acc, int init) {
    int b = blockIdx.x * (blockDim.x >> 6) + (threadIdx.x >> 6);
    int lane = threadIdx.x & 63;
    if (b >= 2 * B) return;
    int row = (b < B) ? users[b] : (nU + items[b - B]);
    float v = x[(size_t)row * 64 + lane];
    size_t o = (size_t)b * 64 + lane;
    if (init) acc[o] = v; else acc[o] += v;
}

// ---------------- SPMM: one wave per dst row, 4 edges in flight, float4 gathers ----
// lane = 16*eidx + f4 : eidx in [0,4) selects edge slot, f4 in [0,16) selects float4
__global__ void k_spmm(const int* __restrict__ row_ptr, const int2* __restrict__ ew,
                       const float* __restrict__ x, float* __restrict__ y, int N) {
    int row = blockIdx.x * (blockDim.x >> 6) + (threadIdx.x >> 6);
    int lane = threadIdx.x & 63;
    int eidx = lane >> 4;
    int f4   = lane & 15;
    if (row >= N) return;
    int s = row_ptr[row], e = row_ptr[row + 1];
    float4 acc = make_float4(0.f, 0.f, 0.f, 0.f);
    for (int j = s + eidx; j < e; j += 4) {
        int2 cw = ew[j];                       // packed (col, w) — one 8B load
        float wt = __int_as_float(cw.y);
        const float4* xr = (const float4*)(x + (size_t)cw.x * 64);
        float4 v = xr[f4];                     // 16B/lane gather
        acc.x += wt * v.x;
        acc.y += wt * v.y;
        acc.z += wt * v.z;
        acc.w += wt * v.w;
    }
    // reduce the 4 edge-groups: lanes l, l^16, l^32, l^48
    #pragma unroll
    for (int o = 16; o <= 32; o <<= 1) {
        acc.x += __shfl_xor(acc.x, o, WAVE);
        acc.y += __shfl_xor(acc.y, o, WAVE);
        acc.z += __shfl_xor(acc.z, o, WAVE);
        acc.w += __shfl_xor(acc.w, o, WAVE);
    }
    if (eidx == 0) {
        ((float4*)(y + (size_t)row * 64))[f4] = acc;   // 16 lanes x 16B = 256B store
    }
}

// ---------------- final: gamma[b] = dot(acc_u[b], acc_i[b]) / 25 ----------------
__global__ void k_dot(const float* __restrict__ acc, int B, float* __restrict__ out) {
    int b = blockIdx.x * (blockDim.x >> 6) + (threadIdx.x >> 6);
    int lane = threadIdx.x & 63;
    if (b >= B) return;
    float p = acc[(size_t)b * 64 + lane] * acc[(size_t)(b + B) * 64 + lane];
    #pragma unroll
    for (int o = 32; o > 0; o >>= 1) p += __shfl_down(p, o, WAVE);
    if (lane == 0) out[b] = p * (1.0f / 25.0f);
}

extern "C" void kernel_launch(void* const* d_in, const int* in_sizes, int n_in,
                              void* d_out, int out_size, void* d_ws, size_t ws_size,
                              hipStream_t stream) {
    const int*   users = (const int*)d_in[0];
    const int*   items = (const int*)d_in[1];
    const int*   eu    = (const int*)d_in[2];
    const int*   ei    = (const int*)d_in[3];
    const float* ue    = (const float*)d_in[4];
    const float* ie    = (const float*)d_in[5];
    float* out = (float*)d_out;

    const int D  = 64;
    const int B  = in_sizes[0];
    const int nE = in_sizes[2];
    const int nU = in_sizes[4] / D;
    const int nI = in_sizes[5] / D;
    const int N  = nU + nI;

    // ---- carve workspace (256B-aligned chunks) ----
    char* p = (char*)d_ws;
    auto alloc = [&](size_t bytes) -> void* {
        void* r = (void*)p;
        p += (bytes + 255) & ~(size_t)255;
        return r;
    };
    int*   cnt     = (int*)  alloc((size_t)N * 4);
    int*   row_ptr = (int*)  alloc((size_t)(N + 1) * 4);
    int*   cursor  = (int*)  alloc((size_t)N * 4);
    float* inv     = (float*)alloc((size_t)N * 4);
    int2*  ew      = (int2*) alloc((size_t)2 * nE * 8);
    float* xa      = (float*)alloc((size_t)N * D * 4);
    float* xb      = (float*)alloc((size_t)N * D * 4);
    float* acc     = (float*)alloc((size_t)2 * B * D * 4);
    int*   bsum    = (int*)  alloc(4096);  // up to 1024 block sums

    const int nB = (N + 255) / 256;  // 586 for N=150000; must be <= 1024

    // ---- build normalized CSR ----
    hipMemsetAsync(cnt, 0, (size_t)N * 4, stream);
    k_deg<<<(nE + 255) / 256, 256, 0, stream>>>(eu, ei, nE, nU, cnt);
    k_inv<<<(N + 255) / 256, 256, 0, stream>>>(cnt, inv, N);
    k_blocksum<<<nB, 256, 0, stream>>>(cnt, N, bsum);
    k_scanbsum<<<1, 1024, 0, stream>>>(bsum, nB);
    k_scanfinal<<<nB, 256, 0, stream>>>(cnt, bsum, N, row_ptr, cursor);
    k_scatter<<<(nE + 255) / 256, 256, 0, stream>>>(eu, ei, nE, nU, inv, cursor, ew);

    // ---- x0 and batch accumulator init ----
    int nTot4 = N * (D / 4);
    k_initx<<<(nTot4 + 255) / 256, 256, 0, stream>>>(
        (const float4*)ue, (const float4*)ie, nU * (D / 4), nTot4, (float4*)xa);
    k_bacc<<<(2 * B + 3) / 4, 256, 0, stream>>>(users, items, B, nU, xa, acc, 1);

    // ---- 4 propagation layers ----
    float* xin = xa;
    float* xout = xb;
    for (int l = 0; l < 4; l++) {
        k_spmm<<<(N + 3) / 4, 256, 0, stream>>>(row_ptr, ew, xin, xout, N);
        k_bacc<<<(2 * B + 3) / 4, 256, 0, stream>>>(users, items, B, nU, xout, acc, 0);
        float* t = xin; xin = xout; xout = t;
    }

    // ---- final dot ----
    k_dot<<<(B + 3) / 4, 256, 0, stream>>>(acc, B, out);
}